// Round 4
// baseline (119.424 us; speedup 1.0000x reference)
//
#include <hip/hip_runtime.h>

#define B_DIM 4096
#define T_DIM 16384
#define WAVES_PER_BLOCK 4
#define PER_LANE 8
#define CHUNK (64 * PER_LANE)   // 512 samples per wave per iteration
#define NIT (T_DIM / CHUNK)     // 32
#define VSTEP (CHUNK / 4)       // 128 f32x4 per chunk

typedef float f32x4 __attribute__((ext_vector_type(4)));

struct M2 { float a, b, c, d; };  // [[a,b],[c,d]]

__device__ inline M2 m2mul(const M2& X, const M2& Y) {
    M2 r;
    r.a = fmaf(X.a, Y.a, X.b * Y.c);
    r.b = fmaf(X.a, Y.b, X.b * Y.d);
    r.c = fmaf(X.c, Y.a, X.d * Y.c);
    r.d = fmaf(X.c, Y.b, X.d * Y.d);
    return r;
}

__global__ __launch_bounds__(256) void biquad_scan_kernel(
    const float* __restrict__ x, const float* __restrict__ v0in,
    const float* __restrict__ pb0, const float* __restrict__ pb1,
    const float* __restrict__ pb2, const float* __restrict__ pa1,
    const float* __restrict__ pa2,
    float* __restrict__ y, float* __restrict__ vout)
{
    const int lane = threadIdx.x & 63;
    const int wave = threadIdx.x >> 6;
    const int row  = blockIdx.x * WAVES_PER_BLOCK + wave;
    if (row >= B_DIM) return;

    const float b0 = *pb0, b1 = *pb1, b2 = *pb2, a1 = *pa1, a2 = *pa2;
    const float na1 = -a1, na2 = -a2;
    const float c0 = b1 - a1 * b0;   // state-update input coeffs
    const float c1 = b2 - a2 * b0;

    // A = [[-a1, 1], [-a2, 0]]
    M2 A  { na1, 1.0f, na2, 0.0f };
    M2 A2 = m2mul(A, A);
    M2 A3 = m2mul(A2, A);
    M2 A4 = m2mul(A2, A2);
    M2 A5 = m2mul(A4, A);
    M2 A6 = m2mul(A4, A2);
    M2 A7 = m2mul(A4, A3);
    M2 A8 = m2mul(A4, A4);

    // Row-0 of A^k for y-correction: y_k = yz_k + (A^k)[0,:]·v_begin
    const float p1a = A .a, p1b = A .b;
    const float p2a = A2.a, p2b = A2.b;
    const float p3a = A3.a, p3b = A3.b;
    const float p4a = A4.a, p4b = A4.b;
    const float p5a = A5.a, p5b = A5.b;
    const float p6a = A6.a, p6b = A6.b;
    const float p7a = A7.a, p7b = A7.b;

    // S[s] = A^(8*2^s) scan matrices; Q = A^(8*lane); R = A^512.
    M2 S0, S1, S2, S3, S4, S5;
    M2 Q { 1.f, 0.f, 0.f, 1.f };
    M2 M = A8;
    S0 = M; if (lane & 1)  Q = m2mul(M, Q); M = m2mul(M, M);
    S1 = M; if (lane & 2)  Q = m2mul(M, Q); M = m2mul(M, M);
    S2 = M; if (lane & 4)  Q = m2mul(M, Q); M = m2mul(M, M);
    S3 = M; if (lane & 8)  Q = m2mul(M, Q); M = m2mul(M, M);
    S4 = M; if (lane & 16) Q = m2mul(M, Q); M = m2mul(M, M);
    S5 = M; if (lane & 32) Q = m2mul(M, Q); M = m2mul(M, M);
    const M2 R = M;  // A^512

    const float* xr = x + (size_t)row * T_DIM;
    float*       yr = y + (size_t)row * T_DIM;

    float vc0 = v0in[row * 2 + 0];
    float vc1 = v0in[row * 2 + 1];

    // lane owns 8 consecutive samples: two adjacent float4s
    const f32x4* xp = (const f32x4*)xr + 2 * lane;
    f32x4*       yp = (f32x4*)yr + 2 * lane;

    // depth-2 prefetch: current chunk (ca,cb), next chunk (na_,nb_)
    f32x4 ca  = xp[0],     cb  = xp[1];
    f32x4 na_ = xp[VSTEP], nb_ = xp[VSTEP + 1];

    for (int i = 0; i < NIT; ++i) {
        f32x4 ma = {0.f, 0.f, 0.f, 0.f}, mb = {0.f, 0.f, 0.f, 0.f};
        if (i + 2 < NIT) {
            ma = xp[(size_t)(i + 2) * VSTEP];
            mb = xp[(size_t)(i + 2) * VSTEP + 1];
        }

        // ---- zero-start fold over 8 samples; record yz_k = b0*x_k + d0 ----
        float d0 = 0.f, d1 = 0.f;
        float yz0, yz1, yz2, yz3, yz4, yz5, yz6, yz7;
        #define FOLD(xs, yz)                                           \
        {   yz = fmaf((xs), b0, d0);                                   \
            float t0 = fmaf(c0, (xs), fmaf(na1, d0, d1));              \
            float t1 = fmaf(na2, d0, c1 * (xs));                       \
            d0 = t0; d1 = t1; }
        FOLD(ca[0], yz0) FOLD(ca[1], yz1) FOLD(ca[2], yz2) FOLD(ca[3], yz3)
        FOLD(cb[0], yz4) FOLD(cb[1], yz5) FOLD(cb[2], yz6) FOLD(cb[3], yz7)
        #undef FOLD

        // ---- inclusive Hillis-Steele scan across lanes ----
        #define SCAN_STEP(Sm, o)                                        \
        {   float q0 = __shfl_up(d0, (unsigned)(o));                    \
            float q1 = __shfl_up(d1, (unsigned)(o));                    \
            if (lane < (o)) { q0 = 0.f; q1 = 0.f; }                     \
            float t0 = fmaf(Sm.a, q0, fmaf(Sm.b, q1, d0));              \
            float t1 = fmaf(Sm.c, q0, fmaf(Sm.d, q1, d1));              \
            d0 = t0; d1 = t1; }
        SCAN_STEP(S0, 1)
        SCAN_STEP(S1, 2)
        SCAN_STEP(S2, 4)
        SCAN_STEP(S3, 8)
        SCAN_STEP(S4, 16)
        SCAN_STEP(S5, 32)
        #undef SCAN_STEP

        // ---- exclusive shift ----
        float e0 = __shfl_up(d0, 1u);
        float e1 = __shfl_up(d1, 1u);
        if (lane == 0) { e0 = 0.f; e1 = 0.f; }

        // ---- per-lane segment start state ----
        const float vb0 = fmaf(Q.a, vc0, fmaf(Q.b, vc1, e0));
        const float vb1 = fmaf(Q.c, vc0, fmaf(Q.d, vc1, e1));

        // ---- y = yz + (A^k)row0 · v_begin (independent 2 FMA per sample) ----
        f32x4 yo0, yo1;
        yo0[0] = yz0 + vb0;
        yo0[1] = fmaf(p1a, vb0, fmaf(p1b, vb1, yz1));
        yo0[2] = fmaf(p2a, vb0, fmaf(p2b, vb1, yz2));
        yo0[3] = fmaf(p3a, vb0, fmaf(p3b, vb1, yz3));
        yo1[0] = fmaf(p4a, vb0, fmaf(p4b, vb1, yz4));
        yo1[1] = fmaf(p5a, vb0, fmaf(p5b, vb1, yz5));
        yo1[2] = fmaf(p6a, vb0, fmaf(p6b, vb1, yz6));
        yo1[3] = fmaf(p7a, vb0, fmaf(p7b, vb1, yz7));

        yp[(size_t)i * VSTEP]     = yo0;
        yp[(size_t)i * VSTEP + 1] = yo1;

        // ---- carry: v_carry = A^512 * v_carry + d_inclusive[63] ----
        float t0 = __shfl(d0, 63);
        float t1 = __shfl(d1, 63);
        float nv0 = fmaf(R.a, vc0, fmaf(R.b, vc1, t0));
        float nv1 = fmaf(R.c, vc0, fmaf(R.d, vc1, t1));
        vc0 = nv0; vc1 = nv1;

        ca = na_; cb = nb_; na_ = ma; nb_ = mb;
    }

    if (lane == 0) {
        vout[row * 2 + 0] = vc0;
        vout[row * 2 + 1] = vc1;
    }
}

extern "C" void kernel_launch(void* const* d_in, const int* in_sizes, int n_in,
                              void* d_out, int out_size, void* d_ws, size_t ws_size,
                              hipStream_t stream) {
    const float* x   = (const float*)d_in[0];
    const float* v0  = (const float*)d_in[1];
    const float* b0  = (const float*)d_in[2];
    const float* b1  = (const float*)d_in[3];
    const float* b2  = (const float*)d_in[4];
    const float* a1  = (const float*)d_in[5];
    const float* a2  = (const float*)d_in[6];

    float* y    = (float*)d_out;
    float* vout = (float*)d_out + (size_t)B_DIM * T_DIM;

    dim3 grid(B_DIM / WAVES_PER_BLOCK);
    dim3 block(64 * WAVES_PER_BLOCK);
    biquad_scan_kernel<<<grid, block, 0, stream>>>(x, v0, b0, b1, b2, a1, a2, y, vout);
}

// Round 5
// 118.528 us; speedup vs baseline: 1.0076x; 1.0076x over previous
//
#include <hip/hip_runtime.h>

#define B_DIM 4096
#define T_DIM 16384
#define WAVES_PER_BLOCK 4
#define PER_LANE 8
#define CHUNK (64 * PER_LANE)   // 512 samples per wave per iteration
#define NIT (T_DIM / CHUNK)     // 32
#define VSTEP (CHUNK / 4)       // 128 f32x4 per chunk

typedef float f32x4 __attribute__((ext_vector_type(4)));

struct M2 { float a, b, c, d; };  // [[a,b],[c,d]]

__device__ inline M2 m2mul(const M2& X, const M2& Y) {
    M2 r;
    r.a = fmaf(X.a, Y.a, X.b * Y.c);
    r.b = fmaf(X.a, Y.b, X.b * Y.d);
    r.c = fmaf(X.c, Y.a, X.d * Y.c);
    r.d = fmaf(X.c, Y.b, X.d * Y.d);
    return r;
}

__global__ __launch_bounds__(256) void biquad_scan_kernel(
    const float* __restrict__ x, const float* __restrict__ v0in,
    const float* __restrict__ pb0, const float* __restrict__ pb1,
    const float* __restrict__ pb2, const float* __restrict__ pa1,
    const float* __restrict__ pa2,
    float* __restrict__ y, float* __restrict__ vout)
{
    const int lane = threadIdx.x & 63;
    const int wave = threadIdx.x >> 6;
    const int row  = blockIdx.x * WAVES_PER_BLOCK + wave;
    if (row >= B_DIM) return;

    const float b0 = *pb0, b1 = *pb1, b2 = *pb2, a1 = *pa1, a2 = *pa2;
    const float na1 = -a1, na2 = -a2;
    const float c0 = b1 - a1 * b0;   // state-update input coeffs
    const float c1 = b2 - a2 * b0;

    // A = [[-a1, 1], [-a2, 0]]
    M2 A  { na1, 1.0f, na2, 0.0f };
    M2 A2 = m2mul(A, A);
    M2 A4 = m2mul(A2, A2);
    M2 A8 = m2mul(A4, A4);

    // S[s] = A^(8*2^s) scan matrices; Q = A^(8*lane); R = A^512.
    M2 S0, S1, S2, S3, S4, S5;
    M2 Q { 1.f, 0.f, 0.f, 1.f };
    M2 M = A8;
    S0 = M; if (lane & 1)  Q = m2mul(M, Q); M = m2mul(M, M);
    S1 = M; if (lane & 2)  Q = m2mul(M, Q); M = m2mul(M, M);
    S2 = M; if (lane & 4)  Q = m2mul(M, Q); M = m2mul(M, M);
    S3 = M; if (lane & 8)  Q = m2mul(M, Q); M = m2mul(M, M);
    S4 = M; if (lane & 16) Q = m2mul(M, Q); M = m2mul(M, M);
    S5 = M; if (lane & 32) Q = m2mul(M, Q); M = m2mul(M, M);
    const M2 R = M;  // A^512

    const float* xr = x + (size_t)row * T_DIM;
    float*       yr = y + (size_t)row * T_DIM;

    float vc0 = v0in[row * 2 + 0];
    float vc1 = v0in[row * 2 + 1];

    // lane owns 8 consecutive samples: two adjacent float4s
    const f32x4* xp = (const f32x4*)xr + 2 * lane;
    f32x4*       yp = (f32x4*)yr + 2 * lane;

    // depth-2 prefetch: current chunk (xa,xb), next chunk (nxa,nxb)
    f32x4 xa  = xp[0],     xb  = xp[1];
    f32x4 nxa = xp[VSTEP], nxb = xp[VSTEP + 1];

    for (int i = 0; i < NIT; ++i) {
        f32x4 mxa = {0.f, 0.f, 0.f, 0.f}, mxb = {0.f, 0.f, 0.f, 0.f};
        if (i + 2 < NIT) {
            mxa = xp[(size_t)(i + 2) * VSTEP];
            mxb = xp[(size_t)(i + 2) * VSTEP + 1];
        }

        // ---- zero-start fold over 8 samples ----
        float d0 = c0 * xa[0];
        float d1 = c1 * xa[0];
        #define FOLD(xs)                                               \
        {   float t0 = fmaf(c0, (xs), fmaf(na1, d0, d1));              \
            float t1 = fmaf(na2, d0, c1 * (xs));                       \
            d0 = t0; d1 = t1; }
        FOLD(xa[1]) FOLD(xa[2]) FOLD(xa[3])
        FOLD(xb[0]) FOLD(xb[1]) FOLD(xb[2]) FOLD(xb[3])
        #undef FOLD

        // ---- inclusive Hillis-Steele scan across lanes ----
        #define SCAN_STEP(Sm, o)                                        \
        {   float q0 = __shfl_up(d0, (unsigned)(o));                    \
            float q1 = __shfl_up(d1, (unsigned)(o));                    \
            if (lane < (o)) { q0 = 0.f; q1 = 0.f; }                     \
            float t0 = fmaf(Sm.a, q0, fmaf(Sm.b, q1, d0));              \
            float t1 = fmaf(Sm.c, q0, fmaf(Sm.d, q1, d1));              \
            d0 = t0; d1 = t1; }
        SCAN_STEP(S0, 1)
        SCAN_STEP(S1, 2)
        SCAN_STEP(S2, 4)
        SCAN_STEP(S3, 8)
        SCAN_STEP(S4, 16)
        SCAN_STEP(S5, 32)
        #undef SCAN_STEP

        // ---- exclusive shift ----
        float e0 = __shfl_up(d0, 1u);
        float e1 = __shfl_up(d1, 1u);
        if (lane == 0) { e0 = 0.f; e1 = 0.f; }

        // ---- per-lane segment start state ----
        float v0r = fmaf(Q.a, vc0, fmaf(Q.b, vc1, e0));
        float v1r = fmaf(Q.c, vc0, fmaf(Q.d, vc1, e1));

        // ---- replay 8 samples serially, emit y ----
        f32x4 yo0, yo1;
        #define REPLAY(xs, dst)                                        \
        {   float yy = fmaf((xs), b0, v0r);                            \
            float n0 = fmaf(na1, yy, fmaf((xs), b1, v1r));             \
            float n1 = fmaf(na2, yy, (xs) * b2);                       \
            v0r = n0; v1r = n1; dst = yy; }
        REPLAY(xa[0], yo0[0]) REPLAY(xa[1], yo0[1])
        REPLAY(xa[2], yo0[2]) REPLAY(xa[3], yo0[3])
        REPLAY(xb[0], yo1[0]) REPLAY(xb[1], yo1[1])
        REPLAY(xb[2], yo1[2]) REPLAY(xb[3], yo1[3])
        #undef REPLAY

        yp[(size_t)i * VSTEP]     = yo0;
        yp[(size_t)i * VSTEP + 1] = yo1;

        // ---- carry: v_carry = A^512 * v_carry + d_inclusive[63] ----
        float t0 = __shfl(d0, 63);
        float t1 = __shfl(d1, 63);
        float nv0 = fmaf(R.a, vc0, fmaf(R.b, vc1, t0));
        float nv1 = fmaf(R.c, vc0, fmaf(R.d, vc1, t1));
        vc0 = nv0; vc1 = nv1;

        xa = nxa; xb = nxb; nxa = mxa; nxb = mxb;
    }

    if (lane == 0) {
        vout[row * 2 + 0] = vc0;
        vout[row * 2 + 1] = vc1;
    }
}

extern "C" void kernel_launch(void* const* d_in, const int* in_sizes, int n_in,
                              void* d_out, int out_size, void* d_ws, size_t ws_size,
                              hipStream_t stream) {
    const float* x   = (const float*)d_in[0];
    const float* v0  = (const float*)d_in[1];
    const float* b0  = (const float*)d_in[2];
    const float* b1  = (const float*)d_in[3];
    const float* b2  = (const float*)d_in[4];
    const float* a1  = (const float*)d_in[5];
    const float* a2  = (const float*)d_in[6];

    float* y    = (float*)d_out;
    float* vout = (float*)d_out + (size_t)B_DIM * T_DIM;

    dim3 grid(B_DIM / WAVES_PER_BLOCK);
    dim3 block(64 * WAVES_PER_BLOCK);
    biquad_scan_kernel<<<grid, block, 0, stream>>>(x, v0, b0, b1, b2, a1, a2, y, vout);
}

// Round 6
// 118.014 us; speedup vs baseline: 1.0120x; 1.0044x over previous
//
#include <hip/hip_runtime.h>

#define B_DIM 4096
#define T_DIM 16384
#define WAVES_PER_BLOCK 4
#define CHUNK 512               // two 256-sample sub-blocks per wave-iteration
#define NIT (T_DIM / CHUNK)     // 32
#define VSTEP (CHUNK / 4)       // 128 float4 per chunk

typedef float f32x4 __attribute__((ext_vector_type(4)));

struct M2 { float a, b, c, d; };  // [[a,b],[c,d]]

__device__ inline M2 m2mul(const M2& X, const M2& Y) {
    M2 r;
    r.a = fmaf(X.a, Y.a, X.b * Y.c);
    r.b = fmaf(X.a, Y.b, X.b * Y.d);
    r.c = fmaf(X.c, Y.a, X.d * Y.c);
    r.d = fmaf(X.c, Y.b, X.d * Y.d);
    return r;
}

__global__ __launch_bounds__(256) void biquad_scan_kernel(
    const float* __restrict__ x, const float* __restrict__ v0in,
    const float* __restrict__ pb0, const float* __restrict__ pb1,
    const float* __restrict__ pb2, const float* __restrict__ pa1,
    const float* __restrict__ pa2,
    float* __restrict__ y, float* __restrict__ vout)
{
    const int lane = threadIdx.x & 63;
    const int wave = threadIdx.x >> 6;
    const int row  = blockIdx.x * WAVES_PER_BLOCK + wave;
    if (row >= B_DIM) return;

    const float b0 = *pb0, b1 = *pb1, b2 = *pb2, a1 = *pa1, a2 = *pa2;
    const float na1 = -a1, na2 = -a2;
    const float c0 = b1 - a1 * b0;   // state-update input coeffs
    const float c1 = b2 - a2 * b0;

    // A = [[-a1, 1], [-a2, 0]]
    M2 A  { na1, 1.0f, na2, 0.0f };
    M2 A2 = m2mul(A, A);
    M2 A4 = m2mul(A2, A2);

    // S[s] = A^(4*2^s) scan matrices; Q = A^(4*lane); R = A^256.
    M2 S0, S1, S2, S3, S4, S5;
    M2 Q { 1.f, 0.f, 0.f, 1.f };
    M2 M = A4;
    S0 = M; if (lane & 1)  Q = m2mul(M, Q); M = m2mul(M, M);
    S1 = M; if (lane & 2)  Q = m2mul(M, Q); M = m2mul(M, M);
    S2 = M; if (lane & 4)  Q = m2mul(M, Q); M = m2mul(M, M);
    S3 = M; if (lane & 8)  Q = m2mul(M, Q); M = m2mul(M, M);
    S4 = M; if (lane & 16) Q = m2mul(M, Q); M = m2mul(M, M);
    S5 = M; if (lane & 32) Q = m2mul(M, Q); M = m2mul(M, M);
    const M2 R = M;  // A^256

    const float* xr = x + (size_t)row * T_DIM;
    float*       yr = y + (size_t)row * T_DIM;

    float vc0 = v0in[row * 2 + 0];
    float vc1 = v0in[row * 2 + 1];

    const f32x4* xp = (const f32x4*)xr;
    f32x4*       yp = (f32x4*)yr;

    // depth-2 prefetch; sub-block A = float4[lane], B = float4[64+lane]
    f32x4 cA = xp[lane],         cB = xp[64 + lane];
    f32x4 nA = xp[VSTEP + lane], nB = xp[VSTEP + 64 + lane];

    for (int i = 0; i < NIT; ++i) {
        f32x4 mA = {0.f, 0.f, 0.f, 0.f}, mB = {0.f, 0.f, 0.f, 0.f};
        if (i + 2 < NIT) {
            mA = xp[(size_t)(i + 2) * VSTEP + lane];
            mB = xp[(size_t)(i + 2) * VSTEP + 64 + lane];
        }

        // ---- zero-start folds over each lane's 4 samples (independent) ----
        float dA0 = c0 * cA[0], dA1 = c1 * cA[0];
        float dB0 = c0 * cB[0], dB1 = c1 * cB[0];
        #define FOLD2(xsA, xsB)                                          \
        {   float tA0 = fmaf(c0, (xsA), fmaf(na1, dA0, dA1));            \
            float tA1 = fmaf(na2, dA0, c1 * (xsA));                      \
            float tB0 = fmaf(c0, (xsB), fmaf(na1, dB0, dB1));            \
            float tB1 = fmaf(na2, dB0, c1 * (xsB));                      \
            dA0 = tA0; dA1 = tA1; dB0 = tB0; dB1 = tB1; }
        FOLD2(cA[1], cB[1]) FOLD2(cA[2], cB[2]) FOLD2(cA[3], cB[3])
        #undef FOLD2

        // ---- two interleaved (independent) Hillis-Steele scans ----
        #define SCAN2(Sm, o)                                             \
        {   float qA0 = __shfl_up(dA0, (unsigned)(o));                   \
            float qA1 = __shfl_up(dA1, (unsigned)(o));                   \
            float qB0 = __shfl_up(dB0, (unsigned)(o));                   \
            float qB1 = __shfl_up(dB1, (unsigned)(o));                   \
            if (lane < (o)) { qA0 = 0.f; qA1 = 0.f; qB0 = 0.f; qB1 = 0.f; } \
            float tA0 = fmaf(Sm.a, qA0, fmaf(Sm.b, qA1, dA0));           \
            float tA1 = fmaf(Sm.c, qA0, fmaf(Sm.d, qA1, dA1));           \
            float tB0 = fmaf(Sm.a, qB0, fmaf(Sm.b, qB1, dB0));           \
            float tB1 = fmaf(Sm.c, qB0, fmaf(Sm.d, qB1, dB1));           \
            dA0 = tA0; dA1 = tA1; dB0 = tB0; dB1 = tB1; }
        SCAN2(S0, 1)
        SCAN2(S1, 2)
        SCAN2(S2, 4)
        SCAN2(S3, 8)
        SCAN2(S4, 16)
        SCAN2(S5, 32)
        #undef SCAN2

        // ---- exclusive shifts ----
        float eA0 = __shfl_up(dA0, 1u), eA1 = __shfl_up(dA1, 1u);
        float eB0 = __shfl_up(dB0, 1u), eB1 = __shfl_up(dB1, 1u);
        if (lane == 0) { eA0 = 0.f; eA1 = 0.f; eB0 = 0.f; eB1 = 0.f; }

        // ---- sub-block totals ----
        const float TA0 = __shfl(dA0, 63), TA1 = __shfl(dA1, 63);
        const float TB0 = __shfl(dB0, 63), TB1 = __shfl(dB1, 63);

        // ---- per-lane segment starts ----
        // A starts from vc
        float vA0 = fmaf(Q.a, vc0, fmaf(Q.b, vc1, eA0));
        float vA1 = fmaf(Q.c, vc0, fmaf(Q.d, vc1, eA1));
        // B starts from sB = A^256·vc + TA (uniform)
        const float sB0 = fmaf(R.a, vc0, fmaf(R.b, vc1, TA0));
        const float sB1 = fmaf(R.c, vc0, fmaf(R.d, vc1, TA1));
        float vB0 = fmaf(Q.a, sB0, fmaf(Q.b, sB1, eB0));
        float vB1 = fmaf(Q.c, sB0, fmaf(Q.d, sB1, eB1));

        // ---- replay 4 samples per sub-block (independent chains) ----
        f32x4 yoA, yoB;
        #define REPLAY2(k)                                               \
        {   float xsA = cA[k], xsB = cB[k];                              \
            float yyA = fmaf(xsA, b0, vA0);                              \
            float yyB = fmaf(xsB, b0, vB0);                              \
            float nA0 = fmaf(na1, yyA, fmaf(xsA, b1, vA1));              \
            float nA1 = fmaf(na2, yyA, xsA * b2);                        \
            float nB0 = fmaf(na1, yyB, fmaf(xsB, b1, vB1));              \
            float nB1 = fmaf(na2, yyB, xsB * b2);                        \
            vA0 = nA0; vA1 = nA1; vB0 = nB0; vB1 = nB1;                  \
            yoA[k] = yyA; yoB[k] = yyB; }
        REPLAY2(0) REPLAY2(1) REPLAY2(2) REPLAY2(3)
        #undef REPLAY2

        yp[(size_t)i * VSTEP + lane]      = yoA;
        yp[(size_t)i * VSTEP + 64 + lane] = yoB;

        // ---- carry: vc' = A^256·sB + TB  (= A^512·vc + ...) ----
        const float nv0 = fmaf(R.a, sB0, fmaf(R.b, sB1, TB0));
        const float nv1 = fmaf(R.c, sB0, fmaf(R.d, sB1, TB1));
        vc0 = nv0; vc1 = nv1;

        cA = nA; cB = nB; nA = mA; nB = mB;
    }

    if (lane == 0) {
        vout[row * 2 + 0] = vc0;
        vout[row * 2 + 1] = vc1;
    }
}

extern "C" void kernel_launch(void* const* d_in, const int* in_sizes, int n_in,
                              void* d_out, int out_size, void* d_ws, size_t ws_size,
                              hipStream_t stream) {
    const float* x   = (const float*)d_in[0];
    const float* v0  = (const float*)d_in[1];
    const float* b0  = (const float*)d_in[2];
    const float* b1  = (const float*)d_in[3];
    const float* b2  = (const float*)d_in[4];
    const float* a1  = (const float*)d_in[5];
    const float* a2  = (const float*)d_in[6];

    float* y    = (float*)d_out;
    float* vout = (float*)d_out + (size_t)B_DIM * T_DIM;

    dim3 grid(B_DIM / WAVES_PER_BLOCK);
    dim3 block(64 * WAVES_PER_BLOCK);
    biquad_scan_kernel<<<grid, block, 0, stream>>>(x, v0, b0, b1, b2, a1, a2, y, vout);
}

// Round 7
// 114.504 us; speedup vs baseline: 1.0430x; 1.0306x over previous
//
#include <hip/hip_runtime.h>

#define B_DIM 4096
#define T_DIM 16384
#define WAVES_PER_BLOCK 4
#define CHUNK 256              // samples per wave per iteration (64 lanes * 4)
#define NIT (T_DIM / CHUNK)    // 64

typedef float f32x4 __attribute__((ext_vector_type(4)));

struct M2 { float a, b, c, d; };  // [[a,b],[c,d]]

__device__ inline M2 m2mul(const M2& X, const M2& Y) {
    M2 r;
    r.a = fmaf(X.a, Y.a, X.b * Y.c);
    r.b = fmaf(X.a, Y.b, X.b * Y.d);
    r.c = fmaf(X.c, Y.a, X.d * Y.c);
    r.d = fmaf(X.c, Y.b, X.d * Y.d);
    return r;
}

// DPP mov: returns src moved per CTRL; 0 where source invalid (bound_ctrl)
// or row-masked off (old = 0).
template<int CTRL, int RMASK>
__device__ inline float dpp0(float v) {
    int r = __builtin_amdgcn_update_dpp(0, __builtin_bit_cast(int, v),
                                        CTRL, RMASK, 0xf, true);
    return __builtin_bit_cast(float, r);
}

#define DPP_ROW_SHR(N) (0x110 + (N))
#define DPP_BCAST15    0x142
#define DPP_BCAST31    0x143

__global__ __launch_bounds__(256) void biquad_scan_kernel(
    const float* __restrict__ x, const float* __restrict__ v0in,
    const float* __restrict__ pb0, const float* __restrict__ pb1,
    const float* __restrict__ pb2, const float* __restrict__ pa1,
    const float* __restrict__ pa2,
    float* __restrict__ y, float* __restrict__ vout)
{
    const int lane = threadIdx.x & 63;
    const int wave = threadIdx.x >> 6;
    const int row  = blockIdx.x * WAVES_PER_BLOCK + wave;
    if (row >= B_DIM) return;

    const float b0 = *pb0, b1 = *pb1, b2 = *pb2, a1 = *pa1, a2 = *pa2;
    const float na1 = -a1, na2 = -a2;
    const float c0 = b1 - a1 * b0;   // state-update input coeffs
    const float c1 = b2 - a2 * b0;

    // A = [[-a1, 1], [-a2, 0]]
    M2 A  { na1, 1.0f, na2, 0.0f };
    M2 A2 = m2mul(A, A);
    M2 A4 = m2mul(A2, A2);

    // Uniform powers: S[s] = A^(4*2^s)
    M2 S0, S1, S2, S3, S4, S5;
    M2 M = A4;
    S0 = M; M = m2mul(M, M);
    S1 = M; M = m2mul(M, M);
    S2 = M; M = m2mul(M, M);
    S3 = M; M = m2mul(M, M);
    S4 = M; M = m2mul(M, M);   // A^64 in S4, M = A^128
    S5 = M; M = m2mul(M, M);   // M = A^256
    const M2 R = M;

    // Per-lane Q = A^(4*lane)
    M2 Q { 1.f, 0.f, 0.f, 1.f };
    if (lane & 1)  Q = m2mul(S0, Q);
    if (lane & 2)  Q = m2mul(S1, Q);
    if (lane & 4)  Q = m2mul(S2, Q);
    if (lane & 8)  Q = m2mul(S3, Q);
    if (lane & 16) Q = m2mul(S4, Q);
    if (lane & 32) Q = m2mul(S5, Q);

    // Per-lane P = A^(4*((lane&15)+1)) for the bcast15 cross-row step
    const int l4 = lane & 15;
    M2 P = A4;
    if (l4 & 1) P = m2mul(S0, P);
    if (l4 & 2) P = m2mul(S1, P);
    if (l4 & 4) P = m2mul(S2, P);
    if (l4 & 8) P = m2mul(S3, P);
    // G for bcast31: rows 2 use P, row 3 uses A^64 * P (rows 0,1 get q=0)
    M2 G = (lane >= 48) ? m2mul(S4, P) : P;

    const float* xr = x + (size_t)row * T_DIM;
    float*       yr = y + (size_t)row * T_DIM;

    float vc0 = v0in[row * 2 + 0];
    float vc1 = v0in[row * 2 + 1];

    const f32x4* xp = (const f32x4*)xr;
    f32x4*       yp = (f32x4*)yr;

    // depth-2 prefetch
    f32x4 xv = xp[lane];
    f32x4 xn = xp[64 + lane];

    for (int i = 0; i < NIT; ++i) {
        f32x4 xm = {0.f, 0.f, 0.f, 0.f};
        if (i + 2 < NIT) xm = xp[(size_t)(i + 2) * 64 + lane];

        // ---- zero-start fold over 4 samples ----
        float d0 = c0 * xv[0];
        float d1 = c1 * xv[0];
        #define FOLD(xs)                                               \
        {   float t0 = fmaf(c0, (xs), fmaf(na1, d0, d1));              \
            float t1 = fmaf(na2, d0, c1 * (xs));                       \
            d0 = t0; d1 = t1; }
        FOLD(xv[1]) FOLD(xv[2]) FOLD(xv[3])
        #undef FOLD

        // ---- row-local inclusive scan via DPP row_shr (pure VALU) ----
        #define SCAN_DPP(Sm, o)                                        \
        {   float q0 = dpp0<DPP_ROW_SHR(o), 0xf>(d0);                  \
            float q1 = dpp0<DPP_ROW_SHR(o), 0xf>(d1);                  \
            float t0 = fmaf(Sm.a, q0, fmaf(Sm.b, q1, d0));             \
            float t1 = fmaf(Sm.c, q0, fmaf(Sm.d, q1, d1));             \
            d0 = t0; d1 = t1; }
        SCAN_DPP(S0, 1)
        SCAN_DPP(S1, 2)
        SCAN_DPP(S2, 4)
        SCAN_DPP(S3, 8)
        #undef SCAN_DPP

        // ---- cross-row: bcast15 into rows 1,3 (per-lane P) ----
        {   float q0 = dpp0<DPP_BCAST15, 0xa>(d0);
            float q1 = dpp0<DPP_BCAST15, 0xa>(d1);
            float t0 = fmaf(P.a, q0, fmaf(P.b, q1, d0));
            float t1 = fmaf(P.c, q0, fmaf(P.d, q1, d1));
            d0 = t0; d1 = t1; }
        // ---- cross-row: bcast31 into rows 2,3 (per-lane G) ----
        {   float q0 = dpp0<DPP_BCAST31, 0xc>(d0);
            float q1 = dpp0<DPP_BCAST31, 0xc>(d1);
            float t0 = fmaf(G.a, q0, fmaf(G.b, q1, d0));
            float t1 = fmaf(G.c, q0, fmaf(G.d, q1, d1));
            d0 = t0; d1 = t1; }

        // ---- totals (lane 63) via readlane (VALU, uniform) ----
        const float T0 = __builtin_bit_cast(float,
            __builtin_amdgcn_readlane(__builtin_bit_cast(int, d0), 63));
        const float T1 = __builtin_bit_cast(float,
            __builtin_amdgcn_readlane(__builtin_bit_cast(int, d1), 63));

        // ---- exclusive shift (only remaining cross-lane DS ops) ----
        float e0 = __shfl_up(d0, 1u);
        float e1 = __shfl_up(d1, 1u);
        if (lane == 0) { e0 = 0.f; e1 = 0.f; }

        // ---- per-lane segment start state ----
        float v0r = fmaf(Q.a, vc0, fmaf(Q.b, vc1, e0));
        float v1r = fmaf(Q.c, vc0, fmaf(Q.d, vc1, e1));

        // ---- replay 4 samples, emit y ----
        f32x4 yv;
        #define REPLAY(xs, dst)                                        \
        {   float yy = fmaf((xs), b0, v0r);                            \
            float n0 = fmaf(na1, yy, fmaf((xs), b1, v1r));             \
            float n1 = fmaf(na2, yy, (xs) * b2);                       \
            v0r = n0; v1r = n1; dst = yy; }
        REPLAY(xv[0], yv[0]) REPLAY(xv[1], yv[1])
        REPLAY(xv[2], yv[2]) REPLAY(xv[3], yv[3])
        #undef REPLAY

        yp[(size_t)i * 64 + lane] = yv;

        // ---- carry: v_carry = A^256 * v_carry + total ----
        float nv0 = fmaf(R.a, vc0, fmaf(R.b, vc1, T0));
        float nv1 = fmaf(R.c, vc0, fmaf(R.d, vc1, T1));
        vc0 = nv0; vc1 = nv1;

        xv = xn; xn = xm;
    }

    if (lane == 0) {
        vout[row * 2 + 0] = vc0;
        vout[row * 2 + 1] = vc1;
    }
}

extern "C" void kernel_launch(void* const* d_in, const int* in_sizes, int n_in,
                              void* d_out, int out_size, void* d_ws, size_t ws_size,
                              hipStream_t stream) {
    const float* x   = (const float*)d_in[0];
    const float* v0  = (const float*)d_in[1];
    const float* b0  = (const float*)d_in[2];
    const float* b1  = (const float*)d_in[3];
    const float* b2  = (const float*)d_in[4];
    const float* a1  = (const float*)d_in[5];
    const float* a2  = (const float*)d_in[6];

    float* y    = (float*)d_out;
    float* vout = (float*)d_out + (size_t)B_DIM * T_DIM;

    dim3 grid(B_DIM / WAVES_PER_BLOCK);
    dim3 block(64 * WAVES_PER_BLOCK);
    biquad_scan_kernel<<<grid, block, 0, stream>>>(x, v0, b0, b1, b2, a1, a2, y, vout);
}

// Round 8
// 111.297 us; speedup vs baseline: 1.0730x; 1.0288x over previous
//
#include <hip/hip_runtime.h>

#define B_DIM 4096
#define T_DIM 16384
#define NWAVES 4
#define CHUNK 256                 // samples per wave per super-iteration
#define NSUP (T_DIM / (CHUNK * NWAVES))   // 16 super-iterations

typedef float f32x4 __attribute__((ext_vector_type(4)));

struct M2 { float a, b, c, d; };  // [[a,b],[c,d]]

__device__ inline M2 m2mul(const M2& X, const M2& Y) {
    M2 r;
    r.a = fmaf(X.a, Y.a, X.b * Y.c);
    r.b = fmaf(X.a, Y.b, X.b * Y.d);
    r.c = fmaf(X.c, Y.a, X.d * Y.c);
    r.d = fmaf(X.c, Y.b, X.d * Y.d);
    return r;
}

__global__ __launch_bounds__(256) void biquad_scan_kernel(
    const float* __restrict__ x, const float* __restrict__ v0in,
    const float* __restrict__ pb0, const float* __restrict__ pb1,
    const float* __restrict__ pb2, const float* __restrict__ pa1,
    const float* __restrict__ pa2,
    float* __restrict__ y, float* __restrict__ vout)
{
    const int lane = threadIdx.x & 63;
    const int w    = threadIdx.x >> 6;      // wave id within block (0..3)
    const int row  = blockIdx.x;            // one row per block

    const float b0 = *pb0, b1 = *pb1, b2 = *pb2, a1 = *pa1, a2 = *pa2;
    const float na1 = -a1, na2 = -a2;
    const float c0 = b1 - a1 * b0;
    const float c1 = b2 - a2 * b0;

    // A = [[-a1, 1], [-a2, 0]]
    M2 A  { na1, 1.0f, na2, 0.0f };
    M2 A2 = m2mul(A, A);
    M2 A4 = m2mul(A2, A2);

    // S[s] = A^(4*2^s); Q = A^(4*lane); R = A^256
    M2 S0, S1, S2, S3, S4, S5;
    M2 Q { 1.f, 0.f, 0.f, 1.f };
    M2 M = A4;
    S0 = M; if (lane & 1)  Q = m2mul(M, Q); M = m2mul(M, M);
    S1 = M; if (lane & 2)  Q = m2mul(M, Q); M = m2mul(M, M);
    S2 = M; if (lane & 4)  Q = m2mul(M, Q); M = m2mul(M, M);
    S3 = M; if (lane & 8)  Q = m2mul(M, Q); M = m2mul(M, M);
    S4 = M; if (lane & 16) Q = m2mul(M, Q); M = m2mul(M, M);
    S5 = M; if (lane & 32) Q = m2mul(M, Q); M = m2mul(M, M);
    const M2 R = M;  // A^256

    __shared__ float Tb[2][NWAVES][2];      // double-buffered chunk totals

    const f32x4* xp = (const f32x4*)(x + (size_t)row * T_DIM);
    f32x4*       yp = (f32x4*)(y + (size_t)row * T_DIM);

    float vc0 = v0in[row * 2 + 0];
    float vc1 = v0in[row * 2 + 1];

    // wave w handles chunk c = 4s + w at super-iteration s
    // f32x4 index of chunk c: c*64 + lane
    f32x4 xv = xp[(size_t)(0 * NWAVES + w) * 64 + lane];
    f32x4 xn = xp[(size_t)(1 * NWAVES + w) * 64 + lane];

    for (int s = 0; s < NSUP; ++s) {
        f32x4 xm = {0.f, 0.f, 0.f, 0.f};
        if (s + 2 < NSUP)
            xm = xp[(size_t)((s + 2) * NWAVES + w) * 64 + lane];

        // ---- zero-start fold over this lane's 4 samples ----
        float d0 = c0 * xv[0];
        float d1 = c1 * xv[0];
        #define FOLD(xs)                                               \
        {   float t0 = fmaf(c0, (xs), fmaf(na1, d0, d1));              \
            float t1 = fmaf(na2, d0, c1 * (xs));                       \
            d0 = t0; d1 = t1; }
        FOLD(xv[1]) FOLD(xv[2]) FOLD(xv[3])
        #undef FOLD

        // ---- inclusive Hillis-Steele scan across lanes (R1 method) ----
        #define SCAN_STEP(Sm, o)                                        \
        {   float q0 = __shfl_up(d0, (unsigned)(o));                    \
            float q1 = __shfl_up(d1, (unsigned)(o));                    \
            if (lane < (o)) { q0 = 0.f; q1 = 0.f; }                     \
            float t0 = fmaf(Sm.a, q0, fmaf(Sm.b, q1, d0));              \
            float t1 = fmaf(Sm.c, q0, fmaf(Sm.d, q1, d1));              \
            d0 = t0; d1 = t1; }
        SCAN_STEP(S0, 1)
        SCAN_STEP(S1, 2)
        SCAN_STEP(S2, 4)
        SCAN_STEP(S3, 8)
        SCAN_STEP(S4, 16)
        SCAN_STEP(S5, 32)
        #undef SCAN_STEP

        // ---- exclusive shift + chunk total ----
        float e0 = __shfl_up(d0, 1u);
        float e1 = __shfl_up(d1, 1u);
        if (lane == 0) { e0 = 0.f; e1 = 0.f; }
        const float T0 = __shfl(d0, 63);
        const float T1 = __shfl(d1, 63);

        // ---- publish chunk totals, one barrier ----
        if (lane == 0) { Tb[s & 1][w][0] = T0; Tb[s & 1][w][1] = T1; }
        __syncthreads();

        const float t00 = Tb[s & 1][0][0], t01 = Tb[s & 1][0][1];
        const float t10 = Tb[s & 1][1][0], t11 = Tb[s & 1][1][1];
        const float t20 = Tb[s & 1][2][0], t21 = Tb[s & 1][2][1];
        const float t30 = Tb[s & 1][3][0], t31 = Tb[s & 1][3][1];

        // ---- entry state for this wave's chunk: chain from vc ----
        float s0 = vc0, s1 = vc1;
        #define APPLY(u0, u1)                                          \
        {   float n0 = fmaf(R.a, s0, fmaf(R.b, s1, (u0)));             \
            float n1 = fmaf(R.c, s0, fmaf(R.d, s1, (u1)));             \
            s0 = n0; s1 = n1; }
        if (w > 0) APPLY(t00, t01)
        if (w > 1) APPLY(t10, t11)
        if (w > 2) APPLY(t20, t21)
        #undef APPLY

        // ---- next carry (all waves compute identically from LDS) ----
        {
            float u0 = vc0, u1 = vc1;
            #define APPLYU(q0, q1)                                     \
            {   float n0 = fmaf(R.a, u0, fmaf(R.b, u1, (q0)));         \
                float n1 = fmaf(R.c, u0, fmaf(R.d, u1, (q1)));         \
                u0 = n0; u1 = n1; }
            APPLYU(t00, t01) APPLYU(t10, t11)
            APPLYU(t20, t21) APPLYU(t30, t31)
            #undef APPLYU
            vc0 = u0; vc1 = u1;
        }

        // ---- per-lane segment start state ----
        float v0r = fmaf(Q.a, s0, fmaf(Q.b, s1, e0));
        float v1r = fmaf(Q.c, s0, fmaf(Q.d, s1, e1));

        // ---- replay 4 samples, emit y ----
        f32x4 yv;
        #define REPLAY(xs, dst)                                        \
        {   float yy = fmaf((xs), b0, v0r);                            \
            float n0 = fmaf(na1, yy, fmaf((xs), b1, v1r));             \
            float n1 = fmaf(na2, yy, (xs) * b2);                       \
            v0r = n0; v1r = n1; dst = yy; }
        REPLAY(xv[0], yv[0]) REPLAY(xv[1], yv[1])
        REPLAY(xv[2], yv[2]) REPLAY(xv[3], yv[3])
        #undef REPLAY

        yp[(size_t)(s * NWAVES + w) * 64 + lane] = yv;

        xv = xn; xn = xm;
    }

    if (threadIdx.x == 0) {
        vout[row * 2 + 0] = vc0;
        vout[row * 2 + 1] = vc1;
    }
}

extern "C" void kernel_launch(void* const* d_in, const int* in_sizes, int n_in,
                              void* d_out, int out_size, void* d_ws, size_t ws_size,
                              hipStream_t stream) {
    const float* x   = (const float*)d_in[0];
    const float* v0  = (const float*)d_in[1];
    const float* b0  = (const float*)d_in[2];
    const float* b1  = (const float*)d_in[3];
    const float* b2  = (const float*)d_in[4];
    const float* a1  = (const float*)d_in[5];
    const float* a2  = (const float*)d_in[6];

    float* y    = (float*)d_out;
    float* vout = (float*)d_out + (size_t)B_DIM * T_DIM;

    dim3 grid(B_DIM);          // one row per block
    dim3 block(64 * NWAVES);
    biquad_scan_kernel<<<grid, block, 0, stream>>>(x, v0, b0, b1, b2, a1, a2, y, vout);
}